// Round 17
// baseline (400.780 us; speedup 1.0000x reference)
//
#include <hip/hip_runtime.h>
#include <hip/hip_bf16.h>

#define BIGV 1.0e9f

static constexpr int B_ = 32;
static constexpr int L_ = 1024;
static constexpr int F_ = 128;
static constexpr int UD2_ = 592;      // skewed u-rows per stream (574 used + prefetch slack)
static constexpr int LAGP_ = 96;      // wave1 lag in pair-steps (6 phases of 16; margin 26 cols)
static constexpr int NSEGP_ = 42;     // phases: 36 + 6
static constexpr size_t STREAM_US = (size_t)B_ * 2 * UD2_ * 1024;  // ushorts (77.6 MB)

typedef __attribute__((ext_vector_type(8))) short short8;
typedef __attribute__((ext_vector_type(4))) float f32x4;

// RNE fp32x2 -> packed bf16x2 via the HW instruction
__device__ __forceinline__ unsigned pack2(float x, float y) {
  unsigned r;
  asm("v_cvt_pk_bf16_f32 %0, %1, %2" : "=v"(r) : "v"(x), "v"(y));
  return r;
}

// lane i <- lane i-1, whole-wave (v_mov_b32_dpp wave_shr:1). Lane 0 keeps its
// own value - never consumed (l0-masked).
__device__ __forceinline__ float shfl_up1_dpp(float x) {
  int xi = __float_as_int(x);
  int r = __builtin_amdgcn_update_dpp(xi, xi, 0x138, 0xF, 0xF, false);  // wave_shr:1
  return __int_as_float(r);
}

// quad_perm [1,1,3,3] (code 0xF5): even lanes receive odd neighbor's value
__device__ __forceinline__ float dpp_odd(float x) {
  int xi = __float_as_int(x);
  int r = __builtin_amdgcn_update_dpp(xi, xi, 0xF5, 0xF, 0xF, false);
  return __int_as_float(r);
}

// 3-input min in one VOP3
__device__ __forceinline__ float min3f(float a, float b, float c) {
  float r;
  asm("v_min3_f32 %0, %1, %2, %3" : "=v"(r) : "v"(a), "v"(b), "v"(c));
  return r;
}

// raw v_sqrt_f32 (1-2ulp error vanishes under bf16 rounding)
__device__ __forceinline__ float fsqrt(float x) {
  float r;
  asm("v_sqrt_f32 %0, %1" : "=v"(r) : "v"(x));
  return r;
}

// consumer-side wait: lane0 polls the device-scope tile mask until `need`
// bits set; then an acquire fence before dependent loads. BOUNDED: ~1e6
// polls (~0.2s) >> ~500-poll worst-case legit wait; if exceeded, proceeds
// -> wrong answer (absmax-diagnosable) instead of a hung container.
__device__ __forceinline__ void wait_tiles(unsigned* flag, unsigned need, bool l0) {
  if (l0) {
    int guard = 0;
    while ((atomicOr(flag, 0u) & need) != need) {
      __builtin_amdgcn_s_sleep(8);
      if (++guard > 1000000) break;
    }
  }
  __threadfence();  // acquire for subsequent stream reads
}

// unpack interleaved pair words + two-column chain.
#define PAIR_STEP(C0HEAD, C1HEAD)                                   \
  {                                                                 \
    unsigned wds[8] = {cwA.x, cwA.y, cwA.z, cwA.w,                  \
                       cwB.x, cwB.y, cwB.z, cwB.w};                 \
    float cv0[8], cv1[8];                                           \
    _Pragma("unroll") for (int r = 0; r < 8; ++r) {                 \
      cv0[r] = __uint_as_float(wds[r] << 16);                       \
      cv1[r] = __uint_as_float(wds[r] & 0xFFFF0000u);               \
    }                                                               \
    float nlA[8], nlB[8];                                           \
    float curA = (C0HEAD) + min3f(dg0, up0, left[0]);               \
    nlA[0] = curA;                                                  \
    _Pragma("unroll") for (int r = 1; r < 8; ++r) {                 \
      curA = cv0[r] + min3f(left[r - 1], left[r], curA);            \
      nlA[r] = curA;                                                \
    }                                                               \
    float curB = (C1HEAD) + min3f(up0, up1, nlA[0]);                \
    nlB[0] = curB;                                                  \
    _Pragma("unroll") for (int r = 1; r < 8; ++r) {                 \
      curB = cv1[r] + min3f(nlA[r - 1], nlA[r], curB);              \
      nlB[r] = curB;                                                \
    }                                                               \
    _Pragma("unroll") for (int r = 0; r < 8; ++r) left[r] = nlB[r]; \
    bot0 = nlA[7]; bot1 = nlB[7];                                   \
  }

// v12b: ONE kernel. Blocks 0..31 = dtw (one batch each, v10 code + tile-flag
// gates); blocks 32..2079 = cost tiles (v11 code + in-block norm + flag
// publish), ordered p-major so every batch's low-u tiles complete first.
// Tile (tc,tr) covers u-rows [16p, 16p+80) of stream b*2+(tr>>2), p=4tc+(tr&3);
// u-row R is produced only by tiles p <= R>>4, so dtw phase n needs the
// prefix p <= (tBase+31)>>4 of its stream. u-rows >575 are never written -
// consumed only at fully masked steps (validated garbage-exposure class).
// Deadlock-freedom: producers never wait; 32 dtw blocks < 256 CUs, producers
// retire and drain under any dispatch order; spin additionally bounded.
__global__ __launch_bounds__(512, 1) void fused_kernel(const float* __restrict__ s1,
                                                       const float* __restrict__ s2,
                                                       ushort* __restrict__ stream,
                                                       unsigned* __restrict__ flags,
                                                       float* __restrict__ out) {
  __shared__ __align__(16) ushort sbuf[2 * 128 * 136];  // cost: aL+bL+stage; dtw: hand
  __shared__ float q1[128], q2[128];

  const int bid = blockIdx.x;
  const int tid = threadIdx.x;

  if (bid >= 32) {
    // ======================= cost tile block =======================
    const int c     = bid - 32;
    const int p     = c >> 6;          // 0..31, ubase = 16p
    const int batch = (c >> 1) & 31;
    const int w     = c & 1;           // stream half (rows 0..511 / 512..1023)
    const int tc    = p >> 2;
    const int j     = p & 3;
    const int tr    = w * 4 + j;

    short (*aL)[136] = (short(*)[136])sbuf;
    short (*bL)[136] = (short(*)[136])(sbuf + 128 * 136);
    ushort (*stage)[256] = (ushort(*)[256])sbuf;  // rows 0..79 (40KB < 68KB)

    const float* Ap = s1 + (size_t)batch * L_ * F_ + (size_t)tr * 128 * F_;
    const float* Bp = s2 + (size_t)batch * L_ * F_ + (size_t)tc * 128 * F_;

    if (tid < 128) q1[tid] = 0.0f;
    else if (tid < 256) q2[tid - 128] = 0.0f;
    __syncthreads();

    // staging + in-block norms (f32 accumulation via LDS atomics)
#pragma unroll 4
    for (int it = 0; it < 8; ++it) {
      int idx = it * 2048 + tid * 4;
      int r = idx >> 7, cc = idx & 127;
      float4 va = *(const float4*)(Ap + idx);
      float4 vb = *(const float4*)(Bp + idx);
      *(uint2*)&aL[r][cc] = make_uint2(pack2(va.x, va.y), pack2(va.z, va.w));
      *(uint2*)&bL[r][cc] = make_uint2(pack2(vb.x, vb.y), pack2(vb.z, vb.w));
      atomicAdd(&q1[r], va.x * va.x + va.y * va.y + va.z * va.z + va.w * va.w);
      atomicAdd(&q2[r], vb.x * vb.x + vb.y * vb.y + vb.z * vb.z + vb.w * vb.w);
    }
    __syncthreads();

    const int wave = tid >> 6, lane = tid & 63, quad = lane >> 4, l16 = lane & 15;
    const int m0 = (wave & 3) * 32, n0 = (wave >> 2) * 64;

    f32x4 acc[2][4] = {};
#pragma unroll
    for (int kc = 0; kc < 4; ++kc) {
      short8 af[2], bf[4];
#pragma unroll
      for (int mi = 0; mi < 2; ++mi)
        af[mi] = *(const short8*)&aL[m0 + mi * 16 + l16][kc * 32 + quad * 8];
#pragma unroll
      for (int nj = 0; nj < 4; ++nj)
        bf[nj] = *(const short8*)&bL[n0 + nj * 16 + l16][kc * 32 + quad * 8];
#pragma unroll
      for (int mi = 0; mi < 2; ++mi)
#pragma unroll
        for (int nj = 0; nj < 4; ++nj)
          acc[mi][nj] = __builtin_amdgcn_mfma_f32_16x16x32_bf16(af[mi], bf[nj], acc[mi][nj], 0, 0, 0);
    }

    __syncthreads();  // done reading aL/bL -> reuse as stage

    // epilogue: sqrt-cost -> bf16 pairs at local pair-skew layout
#pragma unroll
    for (int mi = 0; mi < 2; ++mi) {
      int lr0 = m0 + mi * 16 + quad * 4;
      float a0 = q1[lr0 + 0], a1 = q1[lr0 + 1], a2 = q1[lr0 + 2], a3 = q1[lr0 + 3];
#pragma unroll
      for (int nj = 0; nj < 4; ++nj) {
        int lc = n0 + nj * 16 + l16;
        float qc = q2[lc];
        float v0 = fsqrt(fmaxf(a0 + qc - 2.0f * acc[mi][nj][0], 0.0f));
        float v1 = fsqrt(fmaxf(a1 + qc - 2.0f * acc[mi][nj][1], 0.0f));
        float v2 = fsqrt(fmaxf(a2 + qc - 2.0f * acc[mi][nj][2], 0.0f));
        float v3 = fsqrt(fmaxf(a3 + qc - 2.0f * acc[mi][nj][3], 0.0f));
        float o0 = dpp_odd(v0), o1 = dpp_odd(v1), o2 = dpp_odd(v2), o3 = dpp_odd(v3);
        if ((l16 & 1) == 0) {
          int u = (lr0 >> 3) + (lc >> 1);   // <= 15 + 63 = 78 < 80
          uint4 wd = make_uint4(pack2(v0, o0), pack2(v1, o1), pack2(v2, o2), pack2(v3, o3));
          *(uint4*)&stage[u][lr0 * 2] = wd;
        }
      }
    }
    __syncthreads();

    // coalesced write-out: u-row uloc -> global u-row 16p+uloc
    const int slotbase = 256 * j;
    ushort* Sb = stream + ((size_t)(batch * 2 + w) * UD2_ + 16 * p) * 1024 + slotbase;
#pragma unroll
    for (int it = 0; it < 5; ++it) {
      int t = it * 512 + tid;
      if (t < 80 * 32) {
        int u = t >> 5, h = t & 31, g = h >> 1;
        if ((unsigned)(u - g) < 64u)
          *(uint4*)(Sb + (size_t)u * 1024 + g * 16 + (h & 1) * 8) =
              *(const uint4*)&stage[u][g * 16 + (h & 1) * 8];
      }
    }
    __syncthreads();  // all stores issued+drained block-wide
    if (tid == 0) {
      __threadfence();  // release: stream writes visible device-scope
      atomicOr(&flags[batch * 2 + w], 1u << p);
    }
    return;
  }

  // ======================= dtw block (batch = bid) =======================
  if (tid >= 128) {  // idle waves: match the compute waves' barrier count
    for (int n = 0; n < NSEGP_; ++n) __syncthreads();
    return;
  }

  float* hand = (float*)sbuf;  // 1040 floats, aliases cost's sbuf (per-block)

  const int b    = bid;
  const int wave = tid >> 6;
  const int lane = tid & 63;
  const bool l0 = (lane == 0);
  unsigned* flagS = &flags[b * 2 + wave];

  const ushort* src = stream + (size_t)(b * 2 + wave) * UD2_ * 1024 + lane * 16;

  float left[8];
#pragma unroll
  for (int r = 0; r < 8; ++r) left[r] = BIGV;
  float bot0 = BIGV, bot1 = BIGV;
  float shAprev = BIGV, hPv = BIGV, result = 0.0f;
  float2 hR[4];
  float hb0[16], hb1[16];
  uint4 pre0[16], pre1[16];

  // warm-up reads u-rows 0..15 -> needs tile p=0 only
  wait_tiles(flagS, 1u, l0);
#pragma unroll
  for (int i = 0; i < 16; ++i) {
    pre0[i] = *(const uint4*)(src + (size_t)i * 1024);
    pre1[i] = *(const uint4*)(src + (size_t)i * 1024 + 8);
  }

  for (int n = 0; n < NSEGP_; ++n) {
    __syncthreads();
    const int tBase = 16 * n - (wave ? LAGP_ : 0);
    if ((unsigned)tBase >= 576u) continue;

    // this phase prefetches u-rows tBase+16..tBase+31 -> need tiles
    // p <= (tBase+31)>>4 (cap 31; rows >575 unwritten, masked-consumed)
    {
      unsigned P = (unsigned)(tBase + 31) >> 4;
      if (P > 31u) P = 31u;
      unsigned need = (P >= 31u) ? 0xFFFFFFFFu : ((1u << (P + 1)) - 1u);
      wait_tiles(flagS, need, l0);
    }

    const bool fast = (tBase >= 64) & (tBase <= 496);

    if (wave == 0) {
      if (fast) {
#pragma unroll
        for (int k = 0; k < 16; ++k) {
          float shA = shfl_up1_dpp(bot1);
          float shB = shfl_up1_dpp(bot0);
          uint4 cwA = pre0[k], cwB = pre1[k];
          const ushort* p = src + (size_t)(tBase + k + 16) * 1024;  // <= 527 < UD2_
          pre0[k] = *(const uint4*)p;
          pre1[k] = *(const uint4*)(p + 8);
          float dg0 = l0 ? BIGV : shAprev;
          float up0 = l0 ? BIGV : shB;
          float up1 = l0 ? BIGV : shA;
          PAIR_STEP(cv0[0], cv1[0])
          shAprev = shA;
          hb0[k] = bot0; hb1[k] = bot1;
        }
        if (lane == 63) {  // cols 2*tBase-126 .. +31 (all valid in fast window)
          float2* hp = (float2*)&hand[2 * tBase - 126];
#pragma unroll
          for (int q = 0; q < 16; ++q) hp[q] = make_float2(hb0[q], hb1[q]);
        }
      } else {
#pragma unroll
        for (int k = 0; k < 16; ++k) {
          const int t = tBase + k;
          float shA = shfl_up1_dpp(bot1);
          float shB = shfl_up1_dpp(bot0);
          uint4 cwA = pre0[k], cwB = pre1[k];
          const ushort* p = src + (size_t)(tBase + k + 16) * 1024;  // <= 591 < UD2_
          pre0[k] = *(const uint4*)p;
          pre1[k] = *(const uint4*)(p + 8);
          float dg0 = l0 ? ((t == 0) ? 0.0f : BIGV) : shAprev;
          float up0 = l0 ? BIGV : shB;
          float up1 = l0 ? BIGV : shA;
          bool act = ((unsigned)(t - lane) < 512u);
          PAIR_STEP(act ? cv0[0] : BIGV, act ? cv1[0] : BIGV)
          shAprev = shA;
          int jj = 2 * t - 126;
          if (lane == 63 && (unsigned)jj < 1024u) {
            hand[jj] = bot0; hand[jj + 1] = bot1;
          }
        }
      }
    } else {
      if (fast) {
#pragma unroll
        for (int i = 0; i < 4; ++i) hR[i] = *(const float2*)&hand[2 * (tBase + i)];
#pragma unroll
        for (int k = 0; k < 16; ++k) {
          float shA = shfl_up1_dpp(bot1);
          float shB = shfl_up1_dpp(bot0);
          float2 hCur = hR[k & 3];
          uint4 cwA = pre0[k], cwB = pre1[k];
          const ushort* p = src + (size_t)(tBase + k + 16) * 1024;
          pre0[k] = *(const uint4*)p;
          pre1[k] = *(const uint4*)(p + 8);
          hR[k & 3] = *(const float2*)&hand[2 * (tBase + k + 4)];  // idx <= 1031 < 1040
          float dg0 = l0 ? hPv : shAprev;
          float up0 = l0 ? hCur.x : shB;
          float up1 = l0 ? hCur.y : shA;
          PAIR_STEP(cv0[0], cv1[0])
          shAprev = shA;
          hPv = hCur.y;
        }
      } else {
#pragma unroll
        for (int i = 0; i < 4; ++i)
          hR[i] = *(const float2*)&hand[(2 * (tBase + i)) & 1023];
#pragma unroll
        for (int k = 0; k < 16; ++k) {
          const int t = tBase + k;
          float shA = shfl_up1_dpp(bot1);
          float shB = shfl_up1_dpp(bot0);
          float2 hCur = hR[k & 3];
          uint4 cwA = pre0[k], cwB = pre1[k];
          const ushort* p = src + (size_t)(tBase + k + 16) * 1024;
          pre0[k] = *(const uint4*)p;
          pre1[k] = *(const uint4*)(p + 8);
          hR[k & 3] = *(const float2*)&hand[(2 * (t + 4)) & 1023];
          float dg0 = l0 ? hPv : shAprev;   // hPv starts BIGV (t==0 boundary)
          float up0 = l0 ? hCur.x : shB;
          float up1 = l0 ? hCur.y : shA;
          bool act = ((unsigned)(t - lane) < 512u);
          PAIR_STEP(act ? cv0[0] : BIGV, act ? cv1[0] : BIGV)
          shAprev = shA;
          hPv = hCur.y;
          if (t == 574) result = bot1;  // lane63 col 1023: D[1024][1024]
        }
      }
    }
  }
  if (wave == 1 && lane == 63) out[b] = 1.0f / (1.0f + result * (1.0f / 2048.0f));
}

extern "C" void kernel_launch(void* const* d_in, const int* in_sizes, int n_in,
                              void* d_out, int out_size, void* d_ws, size_t ws_size,
                              hipStream_t stream_) {
  const float* s1 = (const float*)d_in[0];
  const float* s2 = (const float*)d_in[1];
  float* out = (float*)d_out;
  ushort* cws = (ushort*)d_ws;
  unsigned* flags = (unsigned*)(cws + STREAM_US);

  hipMemsetAsync(flags, 0, 64 * sizeof(unsigned), stream_);
  fused_kernel<<<dim3(32 + 2048), 512, 0, stream_>>>(s1, s2, cws, flags, out);
}

// Round 18
// 213.286 us; speedup vs baseline: 1.8791x; 1.8791x over previous
//
#include <hip/hip_runtime.h>
#include <hip/hip_bf16.h>

#define BIGV 1.0e9f

static constexpr int B_ = 32;
static constexpr int L_ = 1024;
static constexpr int F_ = 128;
static constexpr int UD2_ = 592;      // skewed u-rows per stream (574 used + prefetch slack)
static constexpr int LAGP_ = 96;      // wave1 lag in pair-steps (6 phases of 16; margin 26 cols)
static constexpr int NSEGP_ = 42;     // phases: 36 + 6
static constexpr size_t STREAM_US = (size_t)B_ * 2 * UD2_ * 1024;  // ushorts (77.6 MB)

typedef __attribute__((ext_vector_type(8))) short short8;
typedef __attribute__((ext_vector_type(4))) float f32x4;

// RNE fp32x2 -> packed bf16x2 via the HW instruction
__device__ __forceinline__ unsigned pack2(float x, float y) {
  unsigned r;
  asm("v_cvt_pk_bf16_f32 %0, %1, %2" : "=v"(r) : "v"(x), "v"(y));
  return r;
}

// lane i <- lane i-1, whole-wave (v_mov_b32_dpp wave_shr:1). Lane 0 keeps its
// own value - never consumed (l0-masked).
__device__ __forceinline__ float shfl_up1_dpp(float x) {
  int xi = __float_as_int(x);
  int r = __builtin_amdgcn_update_dpp(xi, xi, 0x138, 0xF, 0xF, false);  // wave_shr:1
  return __int_as_float(r);
}

// quad_perm [1,1,3,3] (code 0xF5): even lanes receive odd neighbor's value
__device__ __forceinline__ float dpp_odd(float x) {
  int xi = __float_as_int(x);
  int r = __builtin_amdgcn_update_dpp(xi, xi, 0xF5, 0xF, 0xF, false);
  return __int_as_float(r);
}

// 3-input min in one VOP3
__device__ __forceinline__ float min3f(float a, float b, float c) {
  float r;
  asm("v_min3_f32 %0, %1, %2, %3" : "=v"(r) : "v"(a), "v"(b), "v"(c));
  return r;
}

// raw v_sqrt_f32 (1-2ulp error vanishes under bf16 rounding)
__device__ __forceinline__ float fsqrt(float x) {
  float r;
  asm("v_sqrt_f32 %0, %1" : "=v"(r) : "v"(x));
  return r;
}

// one wave per row of 128 floats; nrm[wid] = sum of squares
__global__ void norm_kernel(const float* __restrict__ s1, const float* __restrict__ s2,
                            float* __restrict__ nrm) {
  int gt   = blockIdx.x * blockDim.x + threadIdx.x;
  int wid  = gt >> 6;
  int lane = gt & 63;
  const float* src = (wid < B_ * L_) ? (s1 + (size_t)wid * F_)
                                     : (s2 + (size_t)(wid - B_ * L_) * F_);
  float2 v = ((const float2*)src)[lane];
  float s = v.x * v.x + v.y * v.y;
#pragma unroll
  for (int o = 32; o > 0; o >>= 1) s += __shfl_xor(s, o, 64);
  if (lane == 0) nrm[wid] = s;
}

// cost matrix -> bf16, two PAIR-skewed streams per batch:
// element (r,c): w = r>>9, rl = r&511; stored at
//   stream[(b*2+w)][u = (c>>1) + (rl>>3)][slot = rl*2 + (c&1)]
// (u-row = 1024 ushorts = 2KB; lane l's slice = 16 ushorts = 32B at slot 16l:
//  8 rows x 2 cols interleaved; u = t uniform across the dtw wave).
//
// v11 (measured 211.8us total): 8 waves/block (512 thr). Wave w: rows
// m0=(w&3)*32, cols n0=(w>>2)*64 -> 32x64 subtile, 32 MFMAs (half the
// per-wave serial path of the 4-wave variant); staging 8 iters/thread;
// 16 waves/CU for latency hiding.
__global__ __launch_bounds__(512) void cost_kernel(const float* __restrict__ s1,
                                                   const float* __restrict__ s2,
                                                   ushort* __restrict__ stream,
                                                   const float* __restrict__ nrm) {
  __shared__ __align__(16) ushort sbuf[2 * 128 * 136];  // aL+bL, reused as stage
  __shared__ float q1[128], q2[128];
  short (*aL)[136] = (short(*)[136])sbuf;
  short (*bL)[136] = (short(*)[136])(sbuf + 128 * 136);
  ushort (*stage)[256] = (ushort(*)[256])sbuf;  // rows 0..79 used (40KB < 68KB)

  const int tid = threadIdx.x;
  const int b   = blockIdx.y;
  const int tc  = blockIdx.x & 7;
  const int tr  = blockIdx.x >> 3;

  const float* Ap = s1 + (size_t)b * L_ * F_ + (size_t)tr * 128 * F_;
  const float* Bp = s2 + (size_t)b * L_ * F_ + (size_t)tc * 128 * F_;

#pragma unroll 4
  for (int it = 0; it < 8; ++it) {
    int idx = it * 2048 + tid * 4;
    int r = idx >> 7, cc = idx & 127;
    float4 va = *(const float4*)(Ap + idx);
    float4 vb = *(const float4*)(Bp + idx);
    *(uint2*)&aL[r][cc] = make_uint2(pack2(va.x, va.y), pack2(va.z, va.w));
    *(uint2*)&bL[r][cc] = make_uint2(pack2(vb.x, vb.y), pack2(vb.z, vb.w));
  }
  if (tid < 128) q1[tid] = nrm[(size_t)b * L_ + tr * 128 + tid];
  else if (tid < 256) q2[tid - 128] = nrm[(size_t)B_ * L_ + (size_t)b * L_ + tc * 128 + (tid - 128)];
  __syncthreads();

  const int wave = tid >> 6, lane = tid & 63, quad = lane >> 4, l16 = lane & 15;
  const int m0 = (wave & 3) * 32, n0 = (wave >> 2) * 64;

  f32x4 acc[2][4] = {};
#pragma unroll
  for (int kc = 0; kc < 4; ++kc) {
    short8 af[2], bf[4];
#pragma unroll
    for (int mi = 0; mi < 2; ++mi)
      af[mi] = *(const short8*)&aL[m0 + mi * 16 + l16][kc * 32 + quad * 8];
#pragma unroll
    for (int nj = 0; nj < 4; ++nj)
      bf[nj] = *(const short8*)&bL[n0 + nj * 16 + l16][kc * 32 + quad * 8];
#pragma unroll
    for (int mi = 0; mi < 2; ++mi)
#pragma unroll
      for (int nj = 0; nj < 4; ++nj)
        acc[mi][nj] = __builtin_amdgcn_mfma_f32_16x16x32_bf16(af[mi], bf[nj], acc[mi][nj], 0, 0, 0);
  }

  __syncthreads();  // all waves done reading aL/bL -> safe to reuse as stage

  // epilogue: sqrt-cost -> bf16 pairs, staged at local pair-skew layout.
  // lc parity == l16 parity; even lane merges odd neighbor via quad_perm DPP
  // and writes one uint4 (4 rows x 2 cols interleaved).
#pragma unroll
  for (int mi = 0; mi < 2; ++mi) {
    int lr0 = m0 + mi * 16 + quad * 4;  // 4-aligned; lr0>>3 const over 4 rows
    float a0 = q1[lr0 + 0], a1 = q1[lr0 + 1], a2 = q1[lr0 + 2], a3 = q1[lr0 + 3];
#pragma unroll
    for (int nj = 0; nj < 4; ++nj) {
      int lc = n0 + nj * 16 + l16;
      float qc = q2[lc];
      float v0 = fsqrt(fmaxf(a0 + qc - 2.0f * acc[mi][nj][0], 0.0f));
      float v1 = fsqrt(fmaxf(a1 + qc - 2.0f * acc[mi][nj][1], 0.0f));
      float v2 = fsqrt(fmaxf(a2 + qc - 2.0f * acc[mi][nj][2], 0.0f));
      float v3 = fsqrt(fmaxf(a3 + qc - 2.0f * acc[mi][nj][3], 0.0f));
      float o0 = dpp_odd(v0), o1 = dpp_odd(v1), o2 = dpp_odd(v2), o3 = dpp_odd(v3);
      if ((l16 & 1) == 0) {
        int u = (lr0 >> 3) + (lc >> 1);   // <= 15 + 63 = 78 < 80
        uint4 wd = make_uint4(pack2(v0, o0), pack2(v1, o1), pack2(v2, o2), pack2(v3, o3));
        *(uint4*)&stage[u][lr0 * 2] = wd;  // slots lr0*2..+7; 16B-aligned (lr0%4==0)
      }
    }
  }
  __syncthreads();

  // coalesced write-out: u-row uloc (0..79) -> global u-row ubase+uloc,
  // slot run slotbase..+255 (512B). chunk g covers slots [16g,16g+16);
  // valid iff lc>>1 = uloc-g in [0,64).
  const int w        = tr >> 2;
  const int slotbase = 256 * (tr & 3);
  const int ubase    = tc * 64 + 16 * (tr & 3);
  ushort* Sb = stream + ((size_t)(b * 2 + w) * UD2_ + ubase) * 1024 + slotbase;
#pragma unroll
  for (int it = 0; it < 5; ++it) {
    int t = it * 512 + tid;
    if (t < 80 * 32) {
      int u = t >> 5, h = t & 31, g = h >> 1;
      if ((unsigned)(u - g) < 64u)
        *(uint4*)(Sb + (size_t)u * 1024 + g * 16 + (h & 1) * 8) =
            *(const uint4*)&stage[u][g * 16 + (h & 1) * 8];
    }
  }
}

// unpack interleaved pair words + two-column chain.
#define PAIR_STEP(C0HEAD, C1HEAD)                                   \
  {                                                                 \
    unsigned wds[8] = {cwA.x, cwA.y, cwA.z, cwA.w,                  \
                       cwB.x, cwB.y, cwB.z, cwB.w};                 \
    float cv0[8], cv1[8];                                           \
    _Pragma("unroll") for (int r = 0; r < 8; ++r) {                 \
      cv0[r] = __uint_as_float(wds[r] << 16);                       \
      cv1[r] = __uint_as_float(wds[r] & 0xFFFF0000u);               \
    }                                                               \
    float nlA[8], nlB[8];                                           \
    float curA = (C0HEAD) + min3f(dg0, up0, left[0]);               \
    nlA[0] = curA;                                                  \
    _Pragma("unroll") for (int r = 1; r < 8; ++r) {                 \
      curA = cv0[r] + min3f(left[r - 1], left[r], curA);            \
      nlA[r] = curA;                                                \
    }                                                               \
    float curB = (C1HEAD) + min3f(up0, up1, nlA[0]);                \
    nlB[0] = curB;                                                  \
    _Pragma("unroll") for (int r = 1; r < 8; ++r) {                 \
      curB = cv1[r] + min3f(nlA[r - 1], nlA[r], curB);              \
      nlB[r] = curB;                                                \
    }                                                               \
    _Pragma("unroll") for (int r = 0; r < 8; ++r) left[r] = nlB[r]; \
    bot0 = nlA[7]; bot1 = nlB[7];                                   \
  }

// v10 dtw (measured 102.5us): pair-stepping - 2 columns per step, 576 serial
// steps. shA = dpp(bot1), shB = dpp(bot0); up0 = shB, up1 = shA,
// diag1 = up0, diag0 = prev shA. Wave1 lane0: float2 hand[2t..2t+1].
// Phases of 16 pair-steps; LAGP=96 (margin 26). Fast: tBase in [64,496].
__global__ __launch_bounds__(128, 1) void dtw_kernel(const ushort* __restrict__ stream,
                                                     float* __restrict__ out) {
  __shared__ float hand[1040];

  const int b    = blockIdx.x;
  const int tid  = threadIdx.x;
  const int wave = tid >> 6;
  const int lane = tid & 63;
  const bool l0 = (lane == 0);

  const ushort* src = stream + (size_t)(b * 2 + wave) * UD2_ * 1024 + lane * 16;

  float left[8];
#pragma unroll
  for (int r = 0; r < 8; ++r) left[r] = BIGV;
  float bot0 = BIGV, bot1 = BIGV;
  float shAprev = BIGV, hPv = BIGV, result = 0.0f;
  float2 hR[4];
  float hb0[16], hb1[16];
  uint4 pre0[16], pre1[16];

#pragma unroll
  for (int i = 0; i < 16; ++i) {
    pre0[i] = *(const uint4*)(src + (size_t)i * 1024);
    pre1[i] = *(const uint4*)(src + (size_t)i * 1024 + 8);
  }

  for (int n = 0; n < NSEGP_; ++n) {
    __syncthreads();
    const int tBase = 16 * n - (wave ? LAGP_ : 0);
    if ((unsigned)tBase >= 576u) continue;

    const bool fast = (tBase >= 64) & (tBase <= 496);

    if (wave == 0) {
      if (fast) {
#pragma unroll
        for (int k = 0; k < 16; ++k) {
          float shA = shfl_up1_dpp(bot1);
          float shB = shfl_up1_dpp(bot0);
          uint4 cwA = pre0[k], cwB = pre1[k];
          const ushort* p = src + (size_t)(tBase + k + 16) * 1024;  // <= 527 < UD2_
          pre0[k] = *(const uint4*)p;
          pre1[k] = *(const uint4*)(p + 8);
          float dg0 = l0 ? BIGV : shAprev;
          float up0 = l0 ? BIGV : shB;
          float up1 = l0 ? BIGV : shA;
          PAIR_STEP(cv0[0], cv1[0])
          shAprev = shA;
          hb0[k] = bot0; hb1[k] = bot1;
        }
        if (lane == 63) {  // cols 2*tBase-126 .. +31 (all valid in fast window)
          float2* hp = (float2*)&hand[2 * tBase - 126];
#pragma unroll
          for (int q = 0; q < 16; ++q) hp[q] = make_float2(hb0[q], hb1[q]);
        }
      } else {
#pragma unroll
        for (int k = 0; k < 16; ++k) {
          const int t = tBase + k;
          float shA = shfl_up1_dpp(bot1);
          float shB = shfl_up1_dpp(bot0);
          uint4 cwA = pre0[k], cwB = pre1[k];
          const ushort* p = src + (size_t)(tBase + k + 16) * 1024;  // <= 591 < UD2_
          pre0[k] = *(const uint4*)p;
          pre1[k] = *(const uint4*)(p + 8);
          float dg0 = l0 ? ((t == 0) ? 0.0f : BIGV) : shAprev;
          float up0 = l0 ? BIGV : shB;
          float up1 = l0 ? BIGV : shA;
          bool act = ((unsigned)(t - lane) < 512u);
          PAIR_STEP(act ? cv0[0] : BIGV, act ? cv1[0] : BIGV)
          shAprev = shA;
          int j = 2 * t - 126;
          if (lane == 63 && (unsigned)j < 1024u) {
            hand[j] = bot0; hand[j + 1] = bot1;
          }
        }
      }
    } else {
      if (fast) {
#pragma unroll
        for (int i = 0; i < 4; ++i) hR[i] = *(const float2*)&hand[2 * (tBase + i)];
#pragma unroll
        for (int k = 0; k < 16; ++k) {
          float shA = shfl_up1_dpp(bot1);
          float shB = shfl_up1_dpp(bot0);
          float2 hCur = hR[k & 3];
          uint4 cwA = pre0[k], cwB = pre1[k];
          const ushort* p = src + (size_t)(tBase + k + 16) * 1024;
          pre0[k] = *(const uint4*)p;
          pre1[k] = *(const uint4*)(p + 8);
          hR[k & 3] = *(const float2*)&hand[2 * (tBase + k + 4)];  // idx <= 1031 < 1040
          float dg0 = l0 ? hPv : shAprev;
          float up0 = l0 ? hCur.x : shB;
          float up1 = l0 ? hCur.y : shA;
          PAIR_STEP(cv0[0], cv1[0])
          shAprev = shA;
          hPv = hCur.y;
        }
      } else {
#pragma unroll
        for (int i = 0; i < 4; ++i)
          hR[i] = *(const float2*)&hand[(2 * (tBase + i)) & 1023];
#pragma unroll
        for (int k = 0; k < 16; ++k) {
          const int t = tBase + k;
          float shA = shfl_up1_dpp(bot1);
          float shB = shfl_up1_dpp(bot0);
          float2 hCur = hR[k & 3];
          uint4 cwA = pre0[k], cwB = pre1[k];
          const ushort* p = src + (size_t)(tBase + k + 16) * 1024;
          pre0[k] = *(const uint4*)p;
          pre1[k] = *(const uint4*)(p + 8);
          hR[k & 3] = *(const float2*)&hand[(2 * (t + 4)) & 1023];
          float dg0 = l0 ? hPv : shAprev;   // hPv starts BIGV (t==0 boundary)
          float up0 = l0 ? hCur.x : shB;
          float up1 = l0 ? hCur.y : shA;
          bool act = ((unsigned)(t - lane) < 512u);
          PAIR_STEP(act ? cv0[0] : BIGV, act ? cv1[0] : BIGV)
          shAprev = shA;
          hPv = hCur.y;
          if (t == 574) result = bot1;  // lane63 col 1023: D[1024][1024]
        }
      }
    }
  }
  if (wave == 1 && lane == 63) out[b] = 1.0f / (1.0f + result * (1.0f / 2048.0f));
}

extern "C" void kernel_launch(void* const* d_in, const int* in_sizes, int n_in,
                              void* d_out, int out_size, void* d_ws, size_t ws_size,
                              hipStream_t stream_) {
  const float* s1 = (const float*)d_in[0];
  const float* s2 = (const float*)d_in[1];
  float* out = (float*)d_out;
  ushort* cws = (ushort*)d_ws;
  float* nrm = (float*)(cws + STREAM_US);

  norm_kernel<<<dim3((2 * B_ * L_) / 4), 256, 0, stream_>>>(s1, s2, nrm);
  cost_kernel<<<dim3(64, B_), 512, 0, stream_>>>(s1, s2, cws, nrm);
  dtw_kernel<<<dim3(B_), 128, 0, stream_>>>(cws, out);
}